// Round 1
// baseline (672.903 us; speedup 1.0000x reference)
//
#include <hip/hip_runtime.h>
#include <cstdint>
#include <cstddef>

// MQA: B=2, T=2048, D=2048, H=16, HD=128. fp32 in/out, bf16 MFMA compute.
#define Bq 2
#define Tq 2048
#define Dq 2048
#define Hq 16
#define HDq 128

using f32x4  = __attribute__((ext_vector_type(4))) float;
using short8 = __attribute__((ext_vector_type(8))) short;
typedef unsigned short ushort_t;

#define GLOAD_LDS16(gp, lp)                                                        \
  __builtin_amdgcn_global_load_lds((const __attribute__((address_space(1))) void*)(gp), \
                                   (__attribute__((address_space(3))) void*)(lp), 16, 0, 0)

__device__ inline ushort_t f2bf(float f) {
  uint32_t u = __float_as_uint(f);
  uint32_t r = (u + 0x7FFFu + ((u >> 16) & 1u)) >> 16;
  return (ushort_t)r;
}
__device__ inline float bf2f(ushort_t u) {
  return __uint_as_float(((uint32_t)u) << 16);
}

// ---------------- cast x (fp32 -> bf16), vectorized ----------------
__global__ void cast_f32_bf16(const float* __restrict__ in, ushort_t* __restrict__ out, int n4) {
  int stride = gridDim.x * blockDim.x;
  for (int i = blockIdx.x * blockDim.x + threadIdx.x; i < n4; i += stride) {
    float4 v = reinterpret_cast<const float4*>(in)[i];
    ushort4 u;
    u.x = f2bf(v.x); u.y = f2bf(v.y); u.z = f2bf(v.z); u.w = f2bf(v.w);
    reinterpret_cast<ushort4*>(out)[i] = u;
  }
}

// ---------------- cast + transpose weights: in[R][C] fp32 -> out[C+off][R] bf16 ----------------
__global__ void cast_transpose(const float* __restrict__ in, ushort_t* __restrict__ out,
                               int R, int C, int row_off) {
  __shared__ float tile[32][33];
  int c0 = blockIdx.x * 32, r0 = blockIdx.y * 32;
  int tx = threadIdx.x, ty = threadIdx.y;
#pragma unroll
  for (int i = ty; i < 32; i += 8)
    tile[i][tx] = in[(size_t)(r0 + i) * C + c0 + tx];
  __syncthreads();
#pragma unroll
  for (int i = ty; i < 32; i += 8)
    out[(size_t)(row_off + c0 + i) * R + r0 + tx] = f2bf(tile[tx][i]);
}

// ---------------- bf16 GEMM: C[M][N] = A[M][K] @ BT[N][K]^T + bias ----------------
// 128x128 tile, BK=32, 256 threads = 4 waves (2x2), each wave 64x64 via 4x4 16x16x32 frags.
// OUT_MODE 0: bf16 out. 1: fp32 out. 2: KV special (cols<128 -> K[M][128], cols>=128 -> VT[b][d][t]).
template <int OUT_MODE>
__global__ __launch_bounds__(256, 2) void gemm_bt(
    const ushort_t* __restrict__ A, const ushort_t* __restrict__ BT,
    const float* __restrict__ bias, void* __restrict__ Cout,
    int M, int N, int K,
    ushort_t* __restrict__ Kout, ushort_t* __restrict__ VTout,
    const float* __restrict__ bias2) {
  constexpr int BM = 128, BN = 128, BK = 32;
  __shared__ ushort_t As[BM * BK];  // 8KB, [row][k] row-major
  __shared__ ushort_t Bs[BN * BK];  // 8KB, [nrow][k]
  const int tid = threadIdx.x;
  const int wave = tid >> 6, lane = tid & 63;
  const int wr = wave >> 1, wc = wave & 1;
  const int m0 = blockIdx.y * BM, n0 = blockIdx.x * BN;
  const int lrow = lane & 15, lk8 = (lane >> 4) * 8;

  f32x4 acc[4][4] = {};

  for (int k0 = 0; k0 < K; k0 += BK) {
#pragma unroll
    for (int p = 0; p < 2; ++p) {
      int byteoff = p * 4096 + wave * 1024;  // wave-uniform
      int e = (byteoff >> 1) + lane * 8;     // element within tile
      int r = e >> 5, c = e & 31;
      GLOAD_LDS16(A + (size_t)(m0 + r) * K + k0 + c, (char*)As + byteoff);
      GLOAD_LDS16(BT + (size_t)(n0 + r) * K + k0 + c, (char*)Bs + byteoff);
    }
    __syncthreads();
    short8 af[4], bfr[4];
#pragma unroll
    for (int i = 0; i < 4; ++i)
      af[i] = *(const short8*)&As[(wr * 64 + i * 16 + lrow) * BK + lk8];
#pragma unroll
    for (int i = 0; i < 4; ++i)
      bfr[i] = *(const short8*)&Bs[(wc * 64 + i * 16 + lrow) * BK + lk8];
#pragma unroll
    for (int mi = 0; mi < 4; ++mi)
#pragma unroll
      for (int ni = 0; ni < 4; ++ni)
        acc[mi][ni] = __builtin_amdgcn_mfma_f32_16x16x32_bf16(af[mi], bfr[ni], acc[mi][ni], 0, 0, 0);
    __syncthreads();
  }

  // epilogue: C row = (lane>>4)*4 + j, col = lane&15  (guide-verified C/D layout)
#pragma unroll
  for (int mi = 0; mi < 4; ++mi) {
#pragma unroll
    for (int ni = 0; ni < 4; ++ni) {
      int rbase = m0 + wr * 64 + mi * 16 + (lane >> 4) * 4;
      int col = n0 + wc * 64 + ni * 16 + lrow;
#pragma unroll
      for (int jj = 0; jj < 4; ++jj) {
        int r = rbase + jj;
        float v = acc[mi][ni][jj];
        if (OUT_MODE == 0) {
          ((ushort_t*)Cout)[(size_t)r * N + col] = f2bf(v + bias[col]);
        } else if (OUT_MODE == 1) {
          ((float*)Cout)[(size_t)r * N + col] = v + bias[col];
        } else {
          if (col < HDq) {
            Kout[(size_t)r * HDq + col] = f2bf(v + bias[col]);
          } else {
            int d = col - HDq;
            int b = r >> 11, t = r & (Tq - 1);
            VTout[((size_t)b * HDq + d) * Tq + t] = f2bf(v + bias2[d]);
          }
        }
      }
    }
  }
}

// ---------------- fused causal MQA attention ----------------
// grid (T/64, H, B), block 256 (4 waves). Wave w owns Q rows [qt*64+w*16, +16).
// Q in registers; K[b][t][128] and VT[b][d][t] read direct from global (L2-resident).
__global__ __launch_bounds__(256, 2) void mqa_attn(
    const ushort_t* __restrict__ Qb, const ushort_t* __restrict__ Kb,
    const ushort_t* __restrict__ VTb, ushort_t* __restrict__ Ab) {
  const int qt = blockIdx.x, h = blockIdx.y, b = blockIdx.z;
  const int wave = threadIdx.x >> 6, lane = threadIdx.x & 63;
  const int lrow = lane & 15, lk8 = (lane >> 4) * 8;
  const float scale = 0.08838834764831845f;  // 1/sqrt(128)

  __shared__ ushort_t Pl[4][16][72];  // per-wave P tile, padded (144B row = 16B-aligned, ~2-way banks)

  // Q fragments: q rows = qt*64 + wave*16 + lrow, d = dc*32 + lk8 .. +8
  short8 qf[4];
  const size_t qrow = (size_t)(b * Tq + qt * 64 + wave * 16 + lrow) * Dq + h * HDq;
#pragma unroll
  for (int dc = 0; dc < 4; ++dc)
    qf[dc] = *(const short8*)(Qb + qrow + dc * 32 + lk8);

  f32x4 o[8] = {};
  float m_run[4], l_run[4];
#pragma unroll
  for (int j = 0; j < 4; ++j) { m_run[j] = -1e30f; l_run[j] = 0.f; }

  const int qg_base = qt * 64 + wave * 16 + (lane >> 4) * 4;

  for (int kt = 0; kt <= qt; ++kt) {
    // S = Q @ K^T  (4 col-frags x 4 d-chunks)
    f32x4 s[4] = {};
    const size_t kbase = (size_t)(b * Tq + kt * 64) * HDq;
#pragma unroll
    for (int ni = 0; ni < 4; ++ni) {
#pragma unroll
      for (int dc = 0; dc < 4; ++dc) {
        short8 kf = *(const short8*)(Kb + kbase + (size_t)(ni * 16 + lrow) * HDq + dc * 32 + lk8);
        s[ni] = __builtin_amdgcn_mfma_f32_16x16x32_bf16(qf[dc], kf, s[ni], 0, 0, 0);
      }
    }
    // scale + causal mask
    const bool diag = (kt == qt);
    float sv[4][4], pm[4] = {-1e30f, -1e30f, -1e30f, -1e30f};
#pragma unroll
    for (int ni = 0; ni < 4; ++ni) {
      int kg = kt * 64 + ni * 16 + lrow;
#pragma unroll
      for (int jj = 0; jj < 4; ++jj) {
        float v = s[ni][jj] * scale;
        if (diag && kg > qg_base + jj) v = -1e30f;
        sv[ni][jj] = v;
        pm[jj] = fmaxf(pm[jj], v);
      }
    }
#pragma unroll
    for (int off = 1; off < 16; off <<= 1)
#pragma unroll
      for (int jj = 0; jj < 4; ++jj) pm[jj] = fmaxf(pm[jj], __shfl_xor(pm[jj], off, 64));

    float alpha[4], psum[4];
#pragma unroll
    for (int jj = 0; jj < 4; ++jj) {
      float newm = fmaxf(m_run[jj], pm[jj]);
      alpha[jj] = __expf(m_run[jj] - newm);
      m_run[jj] = newm;
      psum[jj] = 0.f;
    }
#pragma unroll
    for (int ni = 0; ni < 4; ++ni)
#pragma unroll
      for (int jj = 0; jj < 4; ++jj) {
        float p = __expf(sv[ni][jj] - m_run[jj]);
        psum[jj] += p;
        Pl[wave][(lane >> 4) * 4 + jj][ni * 16 + lrow] = f2bf(p);
      }
#pragma unroll
    for (int off = 1; off < 16; off <<= 1)
#pragma unroll
      for (int jj = 0; jj < 4; ++jj) psum[jj] += __shfl_xor(psum[jj], off, 64);
#pragma unroll
    for (int jj = 0; jj < 4; ++jj) l_run[jj] = l_run[jj] * alpha[jj] + psum[jj];
#pragma unroll
    for (int df = 0; df < 8; ++df)
#pragma unroll
      for (int jj = 0; jj < 4; ++jj) o[df][jj] *= alpha[jj];

    __syncthreads();  // P visible (C-layout -> A-layout through LDS)
    short8 pa[2];
#pragma unroll
    for (int kc = 0; kc < 2; ++kc)
      pa[kc] = *(const short8*)&Pl[wave][lrow][kc * 32 + lk8];
    const size_t vtb = (size_t)b * HDq * Tq;
#pragma unroll
    for (int df = 0; df < 8; ++df) {
#pragma unroll
      for (int kc = 0; kc < 2; ++kc) {
        short8 vf = *(const short8*)(VTb + vtb + (size_t)(df * 16 + lrow) * Tq + kt * 64 + kc * 32 + lk8);
        o[df] = __builtin_amdgcn_mfma_f32_16x16x32_bf16(pa[kc], vf, o[df], 0, 0, 0);
      }
    }
    __syncthreads();  // guard P WAR for next iteration
  }

  float inv[4];
#pragma unroll
  for (int jj = 0; jj < 4; ++jj) inv[jj] = 1.f / l_run[jj];
  const size_t orow = (size_t)(b * Tq + qt * 64 + wave * 16 + (lane >> 4) * 4);
#pragma unroll
  for (int df = 0; df < 8; ++df) {
    int col = h * HDq + df * 16 + lrow;
#pragma unroll
    for (int jj = 0; jj < 4; ++jj)
      Ab[(orow + jj) * Dq + col] = f2bf(o[df][jj] * inv[jj]);
  }
}

// ---------------- launch ----------------
extern "C" void kernel_launch(void* const* d_in, const int* in_sizes, int n_in,
                              void* d_out, int out_size, void* d_ws, size_t ws_size,
                              hipStream_t stream) {
  const float* x  = (const float*)d_in[0];
  const float* Wq = (const float*)d_in[1];
  const float* bq = (const float*)d_in[2];
  const float* Wk = (const float*)d_in[3];
  const float* bk = (const float*)d_in[4];
  const float* Wv = (const float*)d_in[5];
  const float* bv = (const float*)d_in[6];
  const float* Wo = (const float*)d_in[7];
  const float* bo = (const float*)d_in[8];
  float* out = (float*)d_out;

  char* ws = (char*)d_ws;
  ushort_t* xb   = (ushort_t*)(ws);                 // 16 MB  (B*T x D bf16)
  ushort_t* WqT  = (ushort_t*)(ws + 16777216);      // 8 MB   (D x D)
  ushort_t* WkvT = (ushort_t*)(ws + 25165824);      // 1 MB   (256 x D: rows 0-127 Wk^T, 128-255 Wv^T)
  ushort_t* WoT  = (ushort_t*)(ws + 26214400);      // 8 MB
  ushort_t* Qb   = (ushort_t*)(ws + 34603008);      // 16 MB  (B*T x D)
  ushort_t* Kb   = (ushort_t*)(ws + 51380224);      // 1 MB   (B*T x 128)
  ushort_t* VTb  = (ushort_t*)(ws + 52428800);      // 1 MB   (B x 128 x T)
  ushort_t* Ab   = (ushort_t*)(ws + 53477376);      // 16 MB  (B*T x D)

  const int MT = Bq * Tq;  // 4096

  cast_f32_bf16<<<2048, 256, 0, stream>>>(x, xb, MT * Dq / 4);
  cast_transpose<<<dim3(Dq / 32, Dq / 32), dim3(32, 8), 0, stream>>>(Wq, WqT, Dq, Dq, 0);
  cast_transpose<<<dim3(HDq / 32, Dq / 32), dim3(32, 8), 0, stream>>>(Wk, WkvT, Dq, HDq, 0);
  cast_transpose<<<dim3(HDq / 32, Dq / 32), dim3(32, 8), 0, stream>>>(Wv, WkvT, Dq, HDq, HDq);
  cast_transpose<<<dim3(Dq / 32, Dq / 32), dim3(32, 8), 0, stream>>>(Wo, WoT, Dq, Dq, 0);

  gemm_bt<0><<<dim3(Dq / 128, MT / 128), 256, 0, stream>>>(
      xb, WqT, bq, Qb, MT, Dq, Dq, nullptr, nullptr, nullptr);
  gemm_bt<2><<<dim3(2, MT / 128), 256, 0, stream>>>(
      xb, WkvT, bk, nullptr, MT, 256, Dq, Kb, VTb, bv);

  mqa_attn<<<dim3(Tq / 64, Hq, Bq), 256, 0, stream>>>(Qb, Kb, VTb, Ab);

  gemm_bt<1><<<dim3(Dq / 128, MT / 128), 256, 0, stream>>>(
      Ab, WoT, bo, out, MT, Dq, Dq, nullptr, nullptr, nullptr);
}

// Round 2
// 327.460 us; speedup vs baseline: 2.0549x; 2.0549x over previous
//
#include <hip/hip_runtime.h>
#include <cstdint>
#include <cstddef>

// MQA: B=2, T=2048, D=2048, H=16, HD=128. fp32 in/out, bf16 MFMA compute.
#define Bq 2
#define Tq 2048
#define Dq 2048
#define Hq 16
#define HDq 128

using f32x4  = __attribute__((ext_vector_type(4))) float;
using short8 = __attribute__((ext_vector_type(8))) short;
typedef unsigned short ushort_t;

#define GLOAD_LDS16(gp, lp)                                                        \
  __builtin_amdgcn_global_load_lds((const __attribute__((address_space(1))) void*)(gp), \
                                   (__attribute__((address_space(3))) void*)(lp), 16, 0, 0)

__device__ inline ushort_t f2bf(float f) {
  uint32_t u = __float_as_uint(f);
  uint32_t r = (u + 0x7FFFu + ((u >> 16) & 1u)) >> 16;
  return (ushort_t)r;
}

// ---------------- cast x (fp32 -> bf16), vectorized ----------------
__global__ void cast_f32_bf16(const float* __restrict__ in, ushort_t* __restrict__ out, int n4) {
  int stride = gridDim.x * blockDim.x;
  for (int i = blockIdx.x * blockDim.x + threadIdx.x; i < n4; i += stride) {
    float4 v = reinterpret_cast<const float4*>(in)[i];
    ushort4 u;
    u.x = f2bf(v.x); u.y = f2bf(v.y); u.z = f2bf(v.z); u.w = f2bf(v.w);
    reinterpret_cast<ushort4*>(out)[i] = u;
  }
}

// ---------------- cast + transpose weights: in[R][C] fp32 -> out[C+off][R] bf16 ----------------
__global__ void cast_transpose(const float* __restrict__ in, ushort_t* __restrict__ out,
                               int R, int C, int row_off) {
  __shared__ float tile[32][33];
  int c0 = blockIdx.x * 32, r0 = blockIdx.y * 32;
  int tx = threadIdx.x, ty = threadIdx.y;
#pragma unroll
  for (int i = ty; i < 32; i += 8)
    tile[i][tx] = in[(size_t)(r0 + i) * C + c0 + tx];
  __syncthreads();
#pragma unroll
  for (int i = ty; i < 32; i += 8)
    out[(size_t)(row_off + c0 + i) * R + r0 + tx] = f2bf(tile[tx][i]);
}

// ---------------- bf16 GEMM: C[M][N] = A[M][K] @ BT[N][K]^T + bias ----------------
// 128x128 tile, BK=32, 256 threads = 4 waves (2x2), each wave 64x64 via 4x4 16x16x32 frags.
// OUT_MODE 0: bf16 out. 1: fp32 out. 2: KV special (cols<128 -> K[M][128], cols>=128 -> VT[b][d][t]).
template <int OUT_MODE>
__global__ __launch_bounds__(256, 2) void gemm_bt(
    const ushort_t* __restrict__ A, const ushort_t* __restrict__ BT,
    const float* __restrict__ bias, void* __restrict__ Cout,
    int M, int N, int K,
    ushort_t* __restrict__ Kout, ushort_t* __restrict__ VTout,
    const float* __restrict__ bias2) {
  constexpr int BM = 128, BN = 128, BK = 32;
  __shared__ ushort_t As[BM * BK];  // 8KB, [row][k] row-major
  __shared__ ushort_t Bs[BN * BK];  // 8KB, [nrow][k]
  const int tid = threadIdx.x;
  const int wave = tid >> 6, lane = tid & 63;
  const int wr = wave >> 1, wc = wave & 1;
  const int m0 = blockIdx.y * BM, n0 = blockIdx.x * BN;
  const int lrow = lane & 15, lk8 = (lane >> 4) * 8;

  f32x4 acc[4][4] = {};

  for (int k0 = 0; k0 < K; k0 += BK) {
#pragma unroll
    for (int p = 0; p < 2; ++p) {
      int byteoff = p * 4096 + wave * 1024;  // wave-uniform
      int e = (byteoff >> 1) + lane * 8;     // element within tile
      int r = e >> 5, c = e & 31;
      GLOAD_LDS16(A + (size_t)(m0 + r) * K + k0 + c, (char*)As + byteoff);
      GLOAD_LDS16(BT + (size_t)(n0 + r) * K + k0 + c, (char*)Bs + byteoff);
    }
    __syncthreads();
    short8 af[4], bfr[4];
#pragma unroll
    for (int i = 0; i < 4; ++i)
      af[i] = *(const short8*)&As[(wr * 64 + i * 16 + lrow) * BK + lk8];
#pragma unroll
    for (int i = 0; i < 4; ++i)
      bfr[i] = *(const short8*)&Bs[(wc * 64 + i * 16 + lrow) * BK + lk8];
#pragma unroll
    for (int mi = 0; mi < 4; ++mi)
#pragma unroll
      for (int ni = 0; ni < 4; ++ni)
        acc[mi][ni] = __builtin_amdgcn_mfma_f32_16x16x32_bf16(af[mi], bfr[ni], acc[mi][ni], 0, 0, 0);
    __syncthreads();
  }

  // epilogue: C row = (lane>>4)*4 + j, col = lane&15
#pragma unroll
  for (int mi = 0; mi < 4; ++mi) {
#pragma unroll
    for (int ni = 0; ni < 4; ++ni) {
      int rbase = m0 + wr * 64 + mi * 16 + (lane >> 4) * 4;
      int col = n0 + wc * 64 + ni * 16 + lrow;
#pragma unroll
      for (int jj = 0; jj < 4; ++jj) {
        int r = rbase + jj;
        float v = acc[mi][ni][jj];
        if (OUT_MODE == 0) {
          ((ushort_t*)Cout)[(size_t)r * N + col] = f2bf(v + bias[col]);
        } else if (OUT_MODE == 1) {
          ((float*)Cout)[(size_t)r * N + col] = v + bias[col];
        } else {
          if (col < HDq) {
            Kout[(size_t)r * HDq + col] = f2bf(v + bias[col]);
          } else {
            int d = col - HDq;
            int b = r >> 11, t = r & (Tq - 1);
            VTout[((size_t)b * HDq + d) * Tq + t] = f2bf(v + bias2[d]);
          }
        }
      }
    }
  }
}

// ---------------- fused causal MQA attention ----------------
// grid (T/128, H, B), block 256 (4 waves). Wave w owns Q rows [qt*128 + w*32, +32) (2 m-frags).
// K (64x128) and VT (128x64) tiles staged in LDS via global_load_lds, XOR-swizzled
// (linear LDS dest + inverse-swizzled global source + swizzled ds_read — rule 21).
__global__ __launch_bounds__(256, 2) void mqa_attn(
    const ushort_t* __restrict__ Qb, const ushort_t* __restrict__ Kb,
    const ushort_t* __restrict__ VTb, ushort_t* __restrict__ Ab) {
  const int qt = blockIdx.x, h = blockIdx.y, b = blockIdx.z;
  const int wave = threadIdx.x >> 6, lane = threadIdx.x & 63;
  const int lrow = lane & 15, lk8 = (lane >> 4) * 8;
  const float scale = 0.08838834764831845f;  // 1/sqrt(128)

  __shared__ ushort_t Ks[64 * 128];   // 16KB, row t (256B), swizzled byte ^= ((t&7)<<4)
  __shared__ ushort_t Vs[128 * 64];   // 16KB, row d (128B), swizzled byte ^= ((d&7)<<4)
  __shared__ ushort_t Pl[4][32][72];  // per-wave P (q x k), +8 pad -> 2-way banks (free)

  // Q fragments: rows qt*128 + wave*32 + mi*16 + lrow, cols h*128 + dc*32 + lk8
  short8 qf[2][4];
#pragma unroll
  for (int mi = 0; mi < 2; ++mi) {
    const size_t qrow = (size_t)(b * Tq + qt * 128 + wave * 32 + mi * 16 + lrow) * Dq + h * HDq;
#pragma unroll
    for (int dc = 0; dc < 4; ++dc)
      qf[mi][dc] = *(const short8*)(Qb + qrow + dc * 32 + lk8);
  }

  f32x4 o[2][8] = {};
  float m_run[2][4], l_run[2][4];
#pragma unroll
  for (int mi = 0; mi < 2; ++mi)
#pragma unroll
    for (int j = 0; j < 4; ++j) { m_run[mi][j] = -1e30f; l_run[mi][j] = 0.f; }

  const size_t vtb = (size_t)b * HDq * Tq;
  const int nkt = 2 * qt + 2;

  for (int kt = 0; kt < nkt; ++kt) {
    // ---- stage K tile + VT tile (pre-swizzled source, linear LDS dest) ----
#pragma unroll
    for (int rnd = 0; rnd < 4; ++rnd) {
      const int base = rnd * 4096 + wave * 1024;       // wave-uniform LDS byte base
      const int L = base + lane * 16;                  // this lane's dest byte
      // K: row r (0..63) of 256B
      {
        int r = L >> 8, c = L & 255;
        int cs = c ^ ((r & 7) << 4);
        GLOAD_LDS16(Kb + (size_t)(b * Tq + kt * 64 + r) * HDq + (cs >> 1), (char*)Ks + base);
      }
      // VT: row r2 (0..127) of 128B
      {
        int r2 = L >> 7, c2 = L & 127;
        int cs2 = c2 ^ ((r2 & 7) << 4);
        GLOAD_LDS16(VTb + vtb + (size_t)r2 * Tq + kt * 64 + (cs2 >> 1), (char*)Vs + base);
      }
    }
    __syncthreads();  // staging complete (vmcnt(0) drained by barrier semantics)

    // ---- QK^T + online softmax, per m-frag ----
#pragma unroll
    for (int mi = 0; mi < 2; ++mi) {
      f32x4 s[4] = {};
#pragma unroll
      for (int ni = 0; ni < 4; ++ni) {
        const int R = ni * 16 + lrow;  // key t within tile
#pragma unroll
        for (int dc = 0; dc < 4; ++dc) {
          const int C = (dc * 64 + lk8 * 2) ^ ((R & 7) << 4);
          short8 kf = *(const short8*)((const char*)Ks + R * 256 + C);
          s[ni] = __builtin_amdgcn_mfma_f32_16x16x32_bf16(qf[mi][dc], kf, s[ni], 0, 0, 0);
        }
      }
      const int qg = qt * 128 + wave * 32 + mi * 16 + ((lane >> 4) << 2);
      const bool domask = (kt * 64 + 63 > qt * 128 + wave * 32 + mi * 16);  // wave-uniform
      float sv[4][4], pm[4] = {-1e30f, -1e30f, -1e30f, -1e30f};
#pragma unroll
      for (int ni = 0; ni < 4; ++ni) {
        const int kg = kt * 64 + ni * 16 + lrow;
#pragma unroll
        for (int jj = 0; jj < 4; ++jj) {
          float v = s[ni][jj] * scale;
          if (domask && kg > qg + jj) v = -1e30f;
          sv[ni][jj] = v;
          pm[jj] = fmaxf(pm[jj], v);
        }
      }
#pragma unroll
      for (int off = 1; off < 16; off <<= 1)
#pragma unroll
        for (int jj = 0; jj < 4; ++jj) pm[jj] = fmaxf(pm[jj], __shfl_xor(pm[jj], off, 64));

      float alpha[4], psum[4];
#pragma unroll
      for (int jj = 0; jj < 4; ++jj) {
        float newm = fmaxf(m_run[mi][jj], pm[jj]);
        alpha[jj] = __expf(m_run[mi][jj] - newm);
        m_run[mi][jj] = newm;
        psum[jj] = 0.f;
      }
#pragma unroll
      for (int ni = 0; ni < 4; ++ni)
#pragma unroll
        for (int jj = 0; jj < 4; ++jj) {
          float p = __expf(sv[ni][jj] - m_run[mi][jj]);
          psum[jj] += p;
          Pl[wave][mi * 16 + (lane >> 4) * 4 + jj][ni * 16 + lrow] = f2bf(p);
        }
#pragma unroll
      for (int off = 1; off < 16; off <<= 1)
#pragma unroll
        for (int jj = 0; jj < 4; ++jj) psum[jj] += __shfl_xor(psum[jj], off, 64);
#pragma unroll
      for (int jj = 0; jj < 4; ++jj) l_run[mi][jj] = l_run[mi][jj] * alpha[jj] + psum[jj];
#pragma unroll
      for (int df = 0; df < 8; ++df)
#pragma unroll
        for (int jj = 0; jj < 4; ++jj) o[mi][df][jj] *= alpha[jj];
    }

    // ---- PV (P per-wave in LDS: same-wave ds ordering, no barrier needed) ----
    short8 pa[2][2];
#pragma unroll
    for (int mi = 0; mi < 2; ++mi)
#pragma unroll
      for (int kc = 0; kc < 2; ++kc)
        pa[mi][kc] = *(const short8*)&Pl[wave][mi * 16 + lrow][kc * 32 + lk8];
#pragma unroll
    for (int df = 0; df < 8; ++df) {
      const int R = df * 16 + lrow;  // d row
#pragma unroll
      for (int kc = 0; kc < 2; ++kc) {
        const int C = (kc * 64 + lk8 * 2) ^ ((R & 7) << 4);
        short8 vf = *(const short8*)((const char*)Vs + R * 128 + C);
#pragma unroll
        for (int mi = 0; mi < 2; ++mi)
          o[mi][df] = __builtin_amdgcn_mfma_f32_16x16x32_bf16(pa[mi][kc], vf, o[mi][df], 0, 0, 0);
      }
    }
    __syncthreads();  // all waves done reading Ks/Vs before next stage
  }

  // ---- epilogue ----
#pragma unroll
  for (int mi = 0; mi < 2; ++mi) {
    float inv[4];
#pragma unroll
    for (int jj = 0; jj < 4; ++jj) inv[jj] = 1.f / l_run[mi][jj];
    const size_t orow = (size_t)(b * Tq + qt * 128 + wave * 32 + mi * 16 + (lane >> 4) * 4);
#pragma unroll
    for (int df = 0; df < 8; ++df) {
      const int col = h * HDq + df * 16 + lrow;
#pragma unroll
      for (int jj = 0; jj < 4; ++jj)
        Ab[(orow + jj) * Dq + col] = f2bf(o[mi][df][jj] * inv[jj]);
    }
  }
}

// ---------------- launch ----------------
extern "C" void kernel_launch(void* const* d_in, const int* in_sizes, int n_in,
                              void* d_out, int out_size, void* d_ws, size_t ws_size,
                              hipStream_t stream) {
  const float* x  = (const float*)d_in[0];
  const float* Wq = (const float*)d_in[1];
  const float* bq = (const float*)d_in[2];
  const float* Wk = (const float*)d_in[3];
  const float* bk = (const float*)d_in[4];
  const float* Wv = (const float*)d_in[5];
  const float* bv = (const float*)d_in[6];
  const float* Wo = (const float*)d_in[7];
  const float* bo = (const float*)d_in[8];
  float* out = (float*)d_out;

  char* ws = (char*)d_ws;
  ushort_t* xb   = (ushort_t*)(ws);                 // 16 MB  (B*T x D bf16)
  ushort_t* WqT  = (ushort_t*)(ws + 16777216);      // 8 MB   (D x D)
  ushort_t* WkvT = (ushort_t*)(ws + 25165824);      // 1 MB   (256 x D)
  ushort_t* WoT  = (ushort_t*)(ws + 26214400);      // 8 MB
  ushort_t* Qb   = (ushort_t*)(ws + 34603008);      // 16 MB  (B*T x D)
  ushort_t* Kb   = (ushort_t*)(ws + 51380224);      // 1 MB   (B*T x 128)
  ushort_t* VTb  = (ushort_t*)(ws + 52428800);      // 1 MB   (B x 128 x T)
  ushort_t* Ab   = (ushort_t*)(ws + 53477376);      // 16 MB  (B*T x D)

  const int MT = Bq * Tq;  // 4096

  cast_f32_bf16<<<2048, 256, 0, stream>>>(x, xb, MT * Dq / 4);
  cast_transpose<<<dim3(Dq / 32, Dq / 32), dim3(32, 8), 0, stream>>>(Wq, WqT, Dq, Dq, 0);
  cast_transpose<<<dim3(HDq / 32, Dq / 32), dim3(32, 8), 0, stream>>>(Wk, WkvT, Dq, HDq, 0);
  cast_transpose<<<dim3(HDq / 32, Dq / 32), dim3(32, 8), 0, stream>>>(Wv, WkvT, Dq, HDq, HDq);
  cast_transpose<<<dim3(Dq / 32, Dq / 32), dim3(32, 8), 0, stream>>>(Wo, WoT, Dq, Dq, 0);

  gemm_bt<0><<<dim3(Dq / 128, MT / 128), 256, 0, stream>>>(
      xb, WqT, bq, Qb, MT, Dq, Dq, nullptr, nullptr, nullptr);
  gemm_bt<2><<<dim3(2, MT / 128), 256, 0, stream>>>(
      xb, WkvT, bk, nullptr, MT, 256, Dq, Kb, VTb, bv);

  mqa_attn<<<dim3(Tq / 128, Hq, Bq), 256, 0, stream>>>(Qb, Kb, VTb, Ab);

  gemm_bt<1><<<dim3(Dq / 128, MT / 128), 256, 0, stream>>>(
      Ab, WoT, bo, out, MT, Dq, Dq, nullptr, nullptr, nullptr);
}